// Round 2
// baseline (351.521 us; speedup 1.0000x reference)
//
#include <hip/hip_runtime.h>

#define TT 200
#define BB 256
#define DD 128
#define HH 128
#define NG 896  // 7*H

typedef _Float16 half8 __attribute__((ext_vector_type(8)));
typedef _Float16 half2v __attribute__((ext_vector_type(2)));
typedef float float4v __attribute__((ext_vector_type(4)));

__device__ __forceinline__ float fdot2_(half2v a, half2v b, float c) {
#if __has_builtin(__builtin_amdgcn_fdot2)
  return __builtin_amdgcn_fdot2(a, b, c, false);
#else
  return c + (float)a[0] * (float)b[0] + (float)a[1] * (float)b[1];
#endif
}

__device__ __forceinline__ float sigmoidf_(float x) { return 1.f / (1.f + __expf(-x)); }
__device__ __forceinline__ float tanhf_(float x) { return 1.f - 2.f / (__expf(2.f * x) + 1.f); }

// Raw barrier: make LDS writes visible, but do NOT drain vmcnt (keep global
// prefetches in flight across the barrier — __syncthreads would drain them).
__device__ __forceinline__ void barrier_fast() {
  asm volatile("s_waitcnt lgkmcnt(0)\n\ts_barrier" ::: "memory");
}

// Transpose + f16-cast the two weight matrices: W[k][j] (k<128, j<896) -> WT[j][k]
__global__ __launch_bounds__(256) void wtrans_k(const float* __restrict__ Wx,
    const float* __restrict__ Wh, _Float16* __restrict__ WxT, _Float16* __restrict__ WhT) {
  int idx = blockIdx.x * 256 + threadIdx.x;
  if (idx < DD * NG) {
    int k = idx / NG, j = idx % NG;
    WxT[j * DD + k] = (_Float16)Wx[idx];
  } else if (idx < 2 * DD * NG) {
    int i2 = idx - DD * NG;
    int k = i2 / NG, j = i2 % NG;
    WhT[j * DD + k] = (_Float16)Wh[i2];
  }
}

// xg GEMM: rows r = (t-t0)*BB + b; xg[r][col] = x[b,t,:]@W_x[:,col] + bias[col]
__global__ __launch_bounds__(256, 2) void xg_gemm_k(const float* __restrict__ x,
    const _Float16* __restrict__ WxT, const float* __restrict__ bias,
    _Float16* __restrict__ xg, int t0) {
  int mt = blockIdx.x / 7, nt = blockIdx.x % 7;
  __shared__ _Float16 Bld[128][136];
  int tid = threadIdx.x;
  for (int i = tid; i < 128 * 16; i += 256) {
    int r = i >> 4, c8 = (i & 15) << 3;
    *(half8*)&Bld[r][c8] = *(const half8*)(WxT + (size_t)(nt * 128 + r) * DD + c8);
  }
  __syncthreads();
  int wv = tid >> 6, l = tid & 63, lr = l & 15, lk8 = (l >> 4) << 3;
  float4v acc[2][8];
#pragma unroll
  for (int a = 0; a < 2; ++a)
#pragma unroll
    for (int q = 0; q < 8; ++q) acc[a][q] = (float4v){0.f, 0.f, 0.f, 0.f};
  size_t abase[2];
#pragma unroll
  for (int mf = 0; mf < 2; ++mf) {
    int R = mt * 128 + wv * 32 + mf * 16 + lr;
    int t = t0 + (R >> 8), b = R & 255;
    abase[mf] = ((size_t)b * TT + t) * DD + lk8;
  }
#pragma unroll
  for (int kk = 0; kk < 4; ++kk) {
    half8 af[2];
#pragma unroll
    for (int mf = 0; mf < 2; ++mf) {
      float4v x0 = *(const float4v*)(x + abase[mf] + kk * 32);
      float4v x1 = *(const float4v*)(x + abase[mf] + kk * 32 + 4);
      half8 a;
      a[0] = (_Float16)x0[0]; a[1] = (_Float16)x0[1]; a[2] = (_Float16)x0[2]; a[3] = (_Float16)x0[3];
      a[4] = (_Float16)x1[0]; a[5] = (_Float16)x1[1]; a[6] = (_Float16)x1[2]; a[7] = (_Float16)x1[3];
      af[mf] = a;
    }
#pragma unroll
    for (int nf = 0; nf < 8; ++nf) {
      half8 bv = *(const half8*)&Bld[nf * 16 + lr][kk * 32 + lk8];
      acc[0][nf] = __builtin_amdgcn_mfma_f32_16x16x32_f16(af[0], bv, acc[0][nf], 0, 0, 0);
      acc[1][nf] = __builtin_amdgcn_mfma_f32_16x16x32_f16(af[1], bv, acc[1][nf], 0, 0, 0);
    }
  }
  int r4 = (l >> 4) << 2;
#pragma unroll
  for (int nf = 0; nf < 8; ++nf) {
    int col = nt * 128 + nf * 16 + lr;
    float bv = bias[col];
#pragma unroll
    for (int mf = 0; mf < 2; ++mf) {
      int row = mt * 128 + wv * 32 + mf * 16 + r4;
#pragma unroll
      for (int rr = 0; rr < 4; ++rr) {
        xg[(size_t)(row + rr) * NG + col] = (_Float16)(acc[mf][nf][rr] + bv);
      }
    }
  }
}

// Recurrence: one block per sample. 448 threads (7 waves), wave g owns gate g.
// Thread j (gate g=j>>6, u=j&63) owns gate columns g*128+u and g*128+u+64,
// weights held in 128 VGPRs (2x16 half8). h broadcast from LDS; state on j<128.
__global__ __launch_bounds__(448, 2) void rec_k(const _Float16* __restrict__ xg,
    const float* __restrict__ dur, const int* __restrict__ rep,
    const _Float16* __restrict__ WhT, float* __restrict__ out,
    _Float16* __restrict__ st_h, float* __restrict__ st_c, float* __restrict__ st_cb,
    int t0, int t1) {
  int b = blockIdx.x, j = threadIdx.x;
  int tend = rep[b];
  if (t0 > tend) return;  // uniform per block
  int tstop = min(t1 - 1, tend);
  __shared__ __align__(16) _Float16 hbuf[HH];
  __shared__ float gbuf[NG];
  __shared__ float dlds[TT];
  int g = j >> 6, u = j & 63;
  int col0 = g * 128 + u;           // col1 = col0 + 64
  half8 w8[2][16];
#pragma unroll
  for (int q = 0; q < 16; ++q) {
    w8[0][q] = *(const half8*)(WhT + (size_t)col0 * DD + q * 8);
    w8[1][q] = *(const half8*)(WhT + (size_t)(col0 + 64) * DD + q * 8);
  }
  for (int i = j; i < TT; i += 448) dlds[i] = dur[b * TT + i];
  float c_s = 0.f, cb_s = 0.f;
  if (j < HH) {
    if (t0 == 0) {
      hbuf[j] = (_Float16)0.f;
    } else {
      hbuf[j] = st_h[b * HH + j];
      c_s = st_c[b * HH + j];
      cb_s = st_cb[b * HH + j];
    }
  }
  __syncthreads();

  const _Float16* xgp0 = xg + (size_t)b * NG + col0;
  const _Float16* xgp1 = xgp0 + 64;
  const size_t stp = (size_t)BB * NG;
  const half8* hp = (const half8*)hbuf;
  int nsteps = tstop - t0 + 1;

  _Float16 cA[8], cB[8], nA[8], nB[8];
#pragma unroll
  for (int i = 0; i < 8; ++i) {
    int tt = min(i, nsteps - 1);
    cA[i] = xgp0[(size_t)tt * stp];
    cB[i] = xgp1[(size_t)tt * stp];
  }

  for (int tb = t0; tb <= tstop; tb += 8) {
    // prefetch next batch of 8 timesteps (clamped; stays in flight across barriers)
#pragma unroll
    for (int i = 0; i < 8; ++i) {
      int tt = min(tb + 8 + i, tstop);
      nA[i] = xgp0[(size_t)(tt - t0) * stp];
      nB[i] = xgp1[(size_t)(tt - t0) * stp];
    }
#pragma unroll
    for (int ph = 0; ph < 8; ++ph) {
      int t = tb + ph;
      if (t <= tstop) {  // block-uniform
        // ---- phase A: g = xg + h @ W_h for 2 columns ----
        float sacc[2][4];
#pragma unroll
        for (int c = 0; c < 2; ++c)
#pragma unroll
          for (int q = 0; q < 4; ++q) sacc[c][q] = 0.f;
#pragma unroll
        for (int q = 0; q < 16; ++q) {
          half8 hv = hp[q];
#pragma unroll
          for (int c = 0; c < 2; ++c) {
            half8 wv = w8[c][q];
#pragma unroll
            for (int p = 0; p < 4; ++p) {
              half2v ha = {hv[2 * p], hv[2 * p + 1]};
              half2v wa = {wv[2 * p], wv[2 * p + 1]};
              sacc[c][q & 3] = fdot2_(ha, wa, sacc[c][q & 3]);
            }
          }
        }
        float g0 = (float)cA[ph] + ((sacc[0][0] + sacc[0][1]) + (sacc[0][2] + sacc[0][3]));
        float g1 = (float)cB[ph] + ((sacc[1][0] + sacc[1][1]) + (sacc[1][2] + sacc[1][3]));
        float a0, a1;
        if (g == 2) { a0 = tanhf_(g0); a1 = tanhf_(g1); }
        else if (g == 6) {
          a0 = fmaxf(g0, 0.f) + log1pf(__expf(-fabsf(g0)));
          a1 = fmaxf(g1, 0.f) + log1pf(__expf(-fabsf(g1)));
        } else { a0 = sigmoidf_(g0); a1 = sigmoidf_(g1); }
        gbuf[col0] = a0;
        gbuf[col0 + 64] = a1;
        barrier_fast();
        // ---- phase B: state update on threads 0..127 ----
        if (j < HH) {
          float iv = gbuf[j], fv = gbuf[HH + j], zv = gbuf[2 * HH + j], ov = gbuf[3 * HH + j];
          float ibv = gbuf[4 * HH + j], fbv = gbuf[5 * HH + j], dv = gbuf[6 * HH + j];
          float dt = dlds[t];
          float cc = fv * c_s + iv * zv;
          cb_s = fbv * cb_s + ibv * zv;
          float cn = cb_s + (cc - cb_s) * __expf(-dv * dt);
          float hn = ov * tanhf_(cn);
          c_s = cn;
          if (t == tend) {
            out[b * HH + j] = hn;
            out[BB * HH + b * HH + j] = cn;
          }
          hbuf[j] = (_Float16)hn;
        }
        barrier_fast();
      }
    }
#pragma unroll
    for (int i = 0; i < 8; ++i) { cA[i] = nA[i]; cB[i] = nB[i]; }
  }
  if (tstop < tend && j < HH) {  // save state for next chunk
    st_h[b * HH + j] = hbuf[j];
    st_c[b * HH + j] = c_s;
    st_cb[b * HH + j] = cb_s;
  }
}

extern "C" void kernel_launch(void* const* d_in, const int* in_sizes, int n_in,
                              void* d_out, int out_size, void* d_ws, size_t ws_size,
                              hipStream_t stream) {
  const float* x = (const float*)d_in[0];
  const float* dur = (const float*)d_in[1];
  const int* rep = (const int*)d_in[2];
  const float* Wx = (const float*)d_in[3];
  const float* Wh = (const float*)d_in[4];
  const float* bias = (const float*)d_in[5];
  float* out = (float*)d_out;
  char* ws = (char*)d_ws;

  size_t off = 0;
  _Float16* WxT = (_Float16*)(ws + off); off += (size_t)NG * DD * 2;
  _Float16* WhT = (_Float16*)(ws + off); off += (size_t)NG * DD * 2;
  _Float16* st_h = (_Float16*)(ws + off); off += (size_t)BB * HH * 2;
  float* st_c = (float*)(ws + off); off += (size_t)BB * HH * 4;
  float* st_cb = (float*)(ws + off); off += (size_t)BB * HH * 4;
  _Float16* xgbuf = (_Float16*)(ws + off);

  size_t avail = ws_size > off ? ws_size - off : 0;
  size_t perT = (size_t)BB * NG * 2;
  int Tc = (int)(avail / perT);
  if (Tc > TT) Tc = TT;
  if (Tc < 1) Tc = 1;

  hipLaunchKernelGGL(wtrans_k, dim3((2 * DD * NG + 255) / 256), dim3(256), 0, stream,
                     Wx, Wh, WxT, WhT);
  for (int t0 = 0; t0 < TT; t0 += Tc) {
    int t1 = t0 + Tc;
    if (t1 > TT) t1 = TT;
    int mtiles = (t1 - t0) * BB / 128;
    hipLaunchKernelGGL(xg_gemm_k, dim3(mtiles * 7), dim3(256), 0, stream,
                       x, WxT, bias, xgbuf, t0);
    hipLaunchKernelGGL(rec_k, dim3(BB), dim3(448), 0, stream,
                       xgbuf, dur, rep, WhT, out, st_h, st_c, st_cb, t0, t1);
  }
}

// Round 3
// 343.683 us; speedup vs baseline: 1.0228x; 1.0228x over previous
//
#include <hip/hip_runtime.h>

#define TT 200
#define BB 256
#define DD 128
#define HH 128
#define NG 896  // 7*H

typedef _Float16 half8 __attribute__((ext_vector_type(8)));
typedef float float4v __attribute__((ext_vector_type(4)));

__device__ __forceinline__ float sigmoidf_(float x) { return 1.f / (1.f + __expf(-x)); }
__device__ __forceinline__ float tanhf_(float x) { return 1.f - 2.f / (__expf(2.f * x) + 1.f); }

// Raw barrier: LDS visibility without draining vmcnt (global prefetches stay in flight).
__device__ __forceinline__ void barrier_fast() {
  asm volatile("s_waitcnt lgkmcnt(0)\n\ts_barrier" ::: "memory");
}

// Transpose + f16-cast: W[k][j] (k<128, j<896) -> WT[j][k]
__global__ __launch_bounds__(256) void wtrans_k(const float* __restrict__ Wx,
    const float* __restrict__ Wh, _Float16* __restrict__ WxT, _Float16* __restrict__ WhT) {
  int idx = blockIdx.x * 256 + threadIdx.x;
  if (idx < DD * NG) {
    int k = idx / NG, j = idx % NG;
    WxT[j * DD + k] = (_Float16)Wx[idx];
  } else if (idx < 2 * DD * NG) {
    int i2 = idx - DD * NG;
    int k = i2 / NG, j = i2 % NG;
    WhT[j * DD + k] = (_Float16)Wh[i2];
  }
}

// xg GEMM: rows r=(t-t0)*BB+b; xg[r][col] = x[b,t,:]@W_x[:,col] + bias[col]  (f16 out)
__global__ __launch_bounds__(256, 2) void xg_gemm_k(const float* __restrict__ x,
    const _Float16* __restrict__ WxT, const float* __restrict__ bias,
    _Float16* __restrict__ xg, int t0) {
  int mt = blockIdx.x / 7, nt = blockIdx.x % 7;
  __shared__ _Float16 Bld[128][136];
  int tid = threadIdx.x;
  for (int i = tid; i < 128 * 16; i += 256) {
    int r = i >> 4, c8 = (i & 15) << 3;
    *(half8*)&Bld[r][c8] = *(const half8*)(WxT + (size_t)(nt * 128 + r) * DD + c8);
  }
  __syncthreads();
  int wv = tid >> 6, l = tid & 63, lr = l & 15, lk8 = (l >> 4) << 3;
  float4v acc[2][8];
#pragma unroll
  for (int a = 0; a < 2; ++a)
#pragma unroll
    for (int q = 0; q < 8; ++q) acc[a][q] = (float4v){0.f, 0.f, 0.f, 0.f};
  size_t abase[2];
#pragma unroll
  for (int mf = 0; mf < 2; ++mf) {
    int R = mt * 128 + wv * 32 + mf * 16 + lr;
    int t = t0 + (R >> 8), b = R & 255;
    abase[mf] = ((size_t)b * TT + t) * DD + lk8;
  }
#pragma unroll
  for (int kk = 0; kk < 4; ++kk) {
    half8 af[2];
#pragma unroll
    for (int mf = 0; mf < 2; ++mf) {
      float4v x0 = *(const float4v*)(x + abase[mf] + kk * 32);
      float4v x1 = *(const float4v*)(x + abase[mf] + kk * 32 + 4);
      half8 a;
      a[0] = (_Float16)x0[0]; a[1] = (_Float16)x0[1]; a[2] = (_Float16)x0[2]; a[3] = (_Float16)x0[3];
      a[4] = (_Float16)x1[0]; a[5] = (_Float16)x1[1]; a[6] = (_Float16)x1[2]; a[7] = (_Float16)x1[3];
      af[mf] = a;
    }
#pragma unroll
    for (int nf = 0; nf < 8; ++nf) {
      half8 bv = *(const half8*)&Bld[nf * 16 + lr][kk * 32 + lk8];
      acc[0][nf] = __builtin_amdgcn_mfma_f32_16x16x32_f16(af[0], bv, acc[0][nf], 0, 0, 0);
      acc[1][nf] = __builtin_amdgcn_mfma_f32_16x16x32_f16(af[1], bv, acc[1][nf], 0, 0, 0);
    }
  }
  int r4 = (l >> 4) << 2;
#pragma unroll
  for (int nf = 0; nf < 8; ++nf) {
    int col = nt * 128 + nf * 16 + lr;
    float bv = bias[col];
#pragma unroll
    for (int mf = 0; mf < 2; ++mf) {
      int row = mt * 128 + wv * 32 + mf * 16 + r4;
#pragma unroll
      for (int rr = 0; rr < 4; ++rr) {
        xg[(size_t)(row + rr) * NG + col] = (_Float16)(acc[mf][nf][rr] + bv);
      }
    }
  }
}

// MFMA recurrence. 1 block / sample, 512 threads (8 waves).
// Wave w, tile tt (0..6): gate columns [tt*128 + w*16, +16). tt == gate index (uniform).
// W_h B-frags in VGPR (28 x half8). A = h broadcast to all 16 rows (4 ds_read_b128/wave).
// acc initialized with xg -> gate preactivation straight out of MFMA chain.
__global__ __launch_bounds__(512, 2) void rec_k(const _Float16* __restrict__ xg,
    const float* __restrict__ dur, const int* __restrict__ rep,
    const _Float16* __restrict__ WhT, float* __restrict__ out,
    _Float16* __restrict__ st_h, float* __restrict__ st_c, float* __restrict__ st_cb,
    int t0, int t1) {
  int b = blockIdx.x, j = threadIdx.x;
  int tend = rep[b];
  if (t0 > tend) return;  // block-uniform
  int tstop = min(t1 - 1, tend);
  __shared__ __align__(16) _Float16 hbuf[HH];
  __shared__ float gbuf[NG];
  __shared__ float dlds[TT];
  int w = j >> 6, l = j & 63, lr = l & 15, lg = l >> 4;
  int w16 = w * 16;

  // B-fragments: wb[tt][kk] = WhT[col=tt*128+w16+lr][k = kk*32 + lg*8 .. +8]
  half8 wb[7][4];
#pragma unroll
  for (int tt = 0; tt < 7; ++tt) {
    int col = tt * 128 + w16 + lr;
#pragma unroll
    for (int kk = 0; kk < 4; ++kk)
      wb[tt][kk] = *(const half8*)(WhT + (size_t)col * DD + kk * 32 + lg * 8);
  }
  for (int i = j; i < TT; i += 512) dlds[i] = dur[b * TT + i];
  float c_s = 0.f, cb_s = 0.f;
  if (j < HH) {
    if (t0 == 0) {
      hbuf[j] = (_Float16)0.f;
    } else {
      hbuf[j] = st_h[b * HH + j];
      c_s = st_c[b * HH + j];
      cb_s = st_cb[b * HH + j];
    }
  }
  __syncthreads();

  const _Float16* xgp = xg + (size_t)b * NG + w16 + lr;  // + tt*128 + step*stp
  const size_t stp = (size_t)BB * NG;
  const char* hb = (const char*)hbuf;
  _Float16 cur0[7], cur1[7], nxt0[7], nxt1[7];
#pragma unroll
  for (int tt = 0; tt < 7; ++tt) {
    cur0[tt] = xgp[tt * 128];
    cur1[tt] = xgp[(size_t)(min(t0 + 1, tstop) - t0) * stp + tt * 128];
  }

#define STEP(T, CUR)                                                            \
  do {                                                                          \
    half8 af[4];                                                                \
    _Pragma("unroll") for (int kk = 0; kk < 4; ++kk)                            \
        af[kk] = *(const half8*)(hb + kk * 64 + lg * 16);                       \
    float4v acc[7];                                                             \
    _Pragma("unroll") for (int tt = 0; tt < 7; ++tt) {                          \
      float xv = (float)CUR[tt];                                                \
      acc[tt] = (float4v){xv, xv, xv, xv};                                      \
    }                                                                           \
    _Pragma("unroll") for (int kk = 0; kk < 4; ++kk)                            \
        _Pragma("unroll") for (int tt = 0; tt < 7; ++tt)                        \
            acc[tt] = __builtin_amdgcn_mfma_f32_16x16x32_f16(af[kk], wb[tt][kk],\
                                                             acc[tt], 0, 0, 0); \
    if (lg == 0) {                                                              \
      _Pragma("unroll") for (int tt = 0; tt < 7; ++tt) {                        \
        float gv = acc[tt][0], av;                                              \
        if (tt == 2) av = tanhf_(gv);                                           \
        else if (tt == 6) av = fmaxf(gv, 0.f) + log1pf(__expf(-fabsf(gv)));     \
        else av = sigmoidf_(gv);                                                \
        gbuf[tt * 128 + w16 + lr] = av;                                         \
      }                                                                         \
    }                                                                           \
    barrier_fast();                                                             \
    if (j < HH) {                                                               \
      float iv = gbuf[j], fv = gbuf[HH + j], zv = gbuf[2 * HH + j];             \
      float ov = gbuf[3 * HH + j], ibv = gbuf[4 * HH + j];                      \
      float fbv = gbuf[5 * HH + j], dv = gbuf[6 * HH + j];                      \
      float dt = dlds[T];                                                       \
      float cc = fv * c_s + iv * zv;                                            \
      cb_s = fbv * cb_s + ibv * zv;                                             \
      float cn = cb_s + (cc - cb_s) * __expf(-dv * dt);                         \
      float hn = ov * tanhf_(cn);                                               \
      c_s = cn;                                                                 \
      if ((T) == tend) {                                                        \
        out[b * HH + j] = hn;                                                   \
        out[BB * HH + b * HH + j] = cn;                                         \
      }                                                                         \
      hbuf[j] = (_Float16)hn;                                                   \
    }                                                                           \
    barrier_fast();                                                             \
  } while (0)

  for (int tb = t0; tb <= tstop; tb += 2) {
#pragma unroll
    for (int tt = 0; tt < 7; ++tt) {  // prefetch 2 steps ahead (clamped)
      nxt0[tt] = xgp[(size_t)(min(tb + 2, tstop) - t0) * stp + tt * 128];
      nxt1[tt] = xgp[(size_t)(min(tb + 3, tstop) - t0) * stp + tt * 128];
    }
    STEP(tb, cur0);
    if (tb + 1 <= tstop) STEP(tb + 1, cur1);
#pragma unroll
    for (int tt = 0; tt < 7; ++tt) { cur0[tt] = nxt0[tt]; cur1[tt] = nxt1[tt]; }
  }
#undef STEP

  if (tstop < tend && j < HH) {  // save state for next chunk
    st_h[b * HH + j] = hbuf[j];
    st_c[b * HH + j] = c_s;
    st_cb[b * HH + j] = cb_s;
  }
}

extern "C" void kernel_launch(void* const* d_in, const int* in_sizes, int n_in,
                              void* d_out, int out_size, void* d_ws, size_t ws_size,
                              hipStream_t stream) {
  const float* x = (const float*)d_in[0];
  const float* dur = (const float*)d_in[1];
  const int* rep = (const int*)d_in[2];
  const float* Wx = (const float*)d_in[3];
  const float* Wh = (const float*)d_in[4];
  const float* bias = (const float*)d_in[5];
  float* out = (float*)d_out;
  char* ws = (char*)d_ws;

  size_t off = 0;
  _Float16* WxT = (_Float16*)(ws + off); off += (size_t)NG * DD * 2;
  _Float16* WhT = (_Float16*)(ws + off); off += (size_t)NG * DD * 2;
  _Float16* st_h = (_Float16*)(ws + off); off += (size_t)BB * HH * 2;
  float* st_c = (float*)(ws + off); off += (size_t)BB * HH * 4;
  float* st_cb = (float*)(ws + off); off += (size_t)BB * HH * 4;
  _Float16* xgbuf = (_Float16*)(ws + off);

  size_t avail = ws_size > off ? ws_size - off : 0;
  size_t perT = (size_t)BB * NG * 2;
  int Tc = (int)(avail / perT);
  if (Tc > TT) Tc = TT;
  if (Tc < 1) Tc = 1;

  hipLaunchKernelGGL(wtrans_k, dim3((2 * DD * NG + 255) / 256), dim3(256), 0, stream,
                     Wx, Wh, WxT, WhT);
  for (int t0 = 0; t0 < TT; t0 += Tc) {
    int t1 = t0 + Tc;
    if (t1 > TT) t1 = TT;
    int mtiles = (t1 - t0) * BB / 128;
    hipLaunchKernelGGL(xg_gemm_k, dim3(mtiles * 7), dim3(256), 0, stream,
                       x, WxT, bias, xgbuf, t0);
    hipLaunchKernelGGL(rec_k, dim3(BB), dim3(512), 0, stream,
                       xgbuf, dur, rep, WhT, out, st_h, st_c, st_cb, t0, t1);
  }
}

// Round 5
// 213.079 us; speedup vs baseline: 1.6497x; 1.6129x over previous
//
#include <hip/hip_runtime.h>

#define TT 200
#define BB 256
#define DD 128
#define HH 128
#define NG 896    // 7*H semantic gate dim
#define NGP 1024  // padded: pcol = u*8 + gate, gate 7 = zero pad

typedef _Float16 half8 __attribute__((ext_vector_type(8)));
typedef float float4v __attribute__((ext_vector_type(4)));

__device__ __forceinline__ float rcpf_(float x) { return __builtin_amdgcn_rcpf(x); }
__device__ __forceinline__ float sigmoidf_(float x) { return rcpf_(1.f + __expf(-x)); }
__device__ __forceinline__ float tanhf_(float x) { return 1.f - 2.f * rcpf_(__expf(2.f * x) + 1.f); }
// softplus(x) = max(x,0) + ln(1+exp(-|x|));  ln(1+z) = log2(1+z)*ln2
__device__ __forceinline__ float softplusf_(float x) {
  return fmaxf(x, 0.f) + 0.69314718056f * __log2f(1.f + __expf(-fabsf(x)));
}

// Weight prep: WxTp[pcol][k] (pcol=u*8+g, padded), WhT[col][k] (semantic), bias_p[pcol]
__global__ __launch_bounds__(256) void wtrans_k(const float* __restrict__ Wx,
    const float* __restrict__ Wh, const float* __restrict__ bias,
    _Float16* __restrict__ WxTp, _Float16* __restrict__ WhT, float* __restrict__ bias_p) {
  int idx = blockIdx.x * 256 + threadIdx.x;
  if (idx < NGP * DD) {  // WxTp
    int pcol = idx >> 7, k = idx & 127;
    int u = pcol >> 3, g = pcol & 7;
    WxTp[idx] = (g < 7) ? (_Float16)Wx[k * NG + g * HH + u] : (_Float16)0.f;
  } else if (idx < NGP * DD + NG * DD) {  // WhT
    int i2 = idx - NGP * DD;
    int col = i2 >> 7, k = i2 & 127;
    WhT[i2] = (_Float16)Wh[k * NG + col];
  } else if (idx < NGP * DD + NG * DD + NGP) {  // bias_p
    int pcol = idx - NGP * DD - NG * DD;
    int u = pcol >> 3, g = pcol & 7;
    bias_p[pcol] = (g < 7) ? bias[g * HH + u] : 0.f;
  }
}

// xg GEMM: rows r=(t-t0)*BB+b; xg[r][pcol] = x[b,t,:]@WxTp[pcol,:] + bias_p[pcol]
__global__ __launch_bounds__(256, 2) void xg_gemm_k(const float* __restrict__ x,
    const _Float16* __restrict__ WxTp, const float* __restrict__ bias_p,
    _Float16* __restrict__ xg, int t0) {
  int mt = blockIdx.x >> 3, nt = blockIdx.x & 7;
  __shared__ _Float16 Bld[128][136];
  int tid = threadIdx.x;
  for (int i = tid; i < 128 * 16; i += 256) {
    int r = i >> 4, c8 = (i & 15) << 3;
    *(half8*)&Bld[r][c8] = *(const half8*)(WxTp + (size_t)(nt * 128 + r) * DD + c8);
  }
  __syncthreads();
  int wv = tid >> 6, l = tid & 63, lr = l & 15, lk8 = (l >> 4) << 3;
  float4v acc[2][8];
#pragma unroll
  for (int a = 0; a < 2; ++a)
#pragma unroll
    for (int q = 0; q < 8; ++q) acc[a][q] = (float4v){0.f, 0.f, 0.f, 0.f};
  size_t abase[2];
#pragma unroll
  for (int mf = 0; mf < 2; ++mf) {
    int R = mt * 128 + wv * 32 + mf * 16 + lr;
    int t = t0 + (R >> 8), b = R & 255;
    abase[mf] = ((size_t)b * TT + t) * DD + lk8;
  }
#pragma unroll
  for (int kk = 0; kk < 4; ++kk) {
    half8 af[2];
#pragma unroll
    for (int mf = 0; mf < 2; ++mf) {
      float4v x0 = *(const float4v*)(x + abase[mf] + kk * 32);
      float4v x1 = *(const float4v*)(x + abase[mf] + kk * 32 + 4);
      half8 a;
      a[0] = (_Float16)x0[0]; a[1] = (_Float16)x0[1]; a[2] = (_Float16)x0[2]; a[3] = (_Float16)x0[3];
      a[4] = (_Float16)x1[0]; a[5] = (_Float16)x1[1]; a[6] = (_Float16)x1[2]; a[7] = (_Float16)x1[3];
      af[mf] = a;
    }
#pragma unroll
    for (int nf = 0; nf < 8; ++nf) {
      half8 bv = *(const half8*)&Bld[nf * 16 + lr][kk * 32 + lk8];
      acc[0][nf] = __builtin_amdgcn_mfma_f32_16x16x32_f16(af[0], bv, acc[0][nf], 0, 0, 0);
      acc[1][nf] = __builtin_amdgcn_mfma_f32_16x16x32_f16(af[1], bv, acc[1][nf], 0, 0, 0);
    }
  }
  int r4 = (l >> 4) << 2;
#pragma unroll
  for (int nf = 0; nf < 8; ++nf) {
    int col = nt * 128 + nf * 16 + lr;
    float bv = bias_p[col];
#pragma unroll
    for (int mf = 0; mf < 2; ++mf) {
      int row = mt * 128 + wv * 32 + mf * 16 + r4;
#pragma unroll
      for (int rr = 0; rr < 4; ++rr) {
        xg[(size_t)(row + rr) * NGP + col] = (_Float16)(acc[mf][nf][rr] + bv);
      }
    }
  }
}

// MFMA recurrence, one __syncthreads per step (compiler-safe barrier).
// 1 block/sample, 512 threads (8 waves). Wave w, lane l: lr=l&15, lg=l>>4.
// Unit u = w*16+lr. A = h broadcast to all 16 rows => acc[tt][0] = gate-tt
// preactivation for unit u (identical across rows/lg). Each lane does the full
// state update for u in registers (4x replicated over lg); lg==0 writes h to the
// double-buffered hbuf and the outputs. xg: ONE aligned half8 per lane per step.
__global__ __launch_bounds__(512, 2) void rec_k(const _Float16* __restrict__ xg,
    const float* __restrict__ dur, const int* __restrict__ rep,
    const _Float16* __restrict__ WhT, float* __restrict__ out,
    _Float16* __restrict__ st_h, float* __restrict__ st_c, float* __restrict__ st_cb,
    int t0, int t1) {
  int b = blockIdx.x, j = threadIdx.x;
  int tend = rep[b];
  if (t0 > tend) return;  // block-uniform
  int tstop = min(t1 - 1, tend);
  __shared__ __align__(16) _Float16 hbuf[2][HH];
  __shared__ float dlds[TT];
  int w = j >> 6, l = j & 63, lr = l & 15, lg = l >> 4;
  int u = w * 16 + lr;

  // B-fragments: wb[tt][kk] = WhT[col = tt*128+u][k = kk*32 + lg*8 .. +8]
  half8 wb[7][4];
#pragma unroll
  for (int tt = 0; tt < 7; ++tt) {
#pragma unroll
    for (int kk = 0; kk < 4; ++kk)
      wb[tt][kk] = *(const half8*)(WhT + (size_t)(tt * HH + u) * DD + kk * 32 + lg * 8);
  }
  for (int i = j; i < TT; i += 512) dlds[i] = dur[b * TT + i];
  float c_s = 0.f, cb_s = 0.f;
  if (lg == 0) {
    if (t0 == 0) {
      hbuf[0][u] = (_Float16)0.f;
    } else {
      hbuf[0][u] = st_h[b * HH + u];
    }
    hbuf[1][u] = (_Float16)0.f;
  }
  if (t0 != 0) {
    c_s = st_c[b * HH + u];
    cb_s = st_cb[b * HH + u];
  }
  __syncthreads();

  const _Float16* xgp = xg + (size_t)b * NGP + u * 8;  // + step*stp, aligned 16B
  const size_t stp = (size_t)BB * NGP;
  half8 cur0, cur1, nxt0, nxt1;
  cur0 = *(const half8*)(xgp);
  cur1 = *(const half8*)(xgp + (size_t)(min(t0 + 1, tstop) - t0) * stp);
  float hsave = 0.f;

#define STEP(T, CUR, PIN, POUT)                                                  \
  do {                                                                           \
    float dt = dlds[T];                                                          \
    half8 af[4];                                                                 \
    _Pragma("unroll") for (int kk = 0; kk < 4; ++kk)                             \
        af[kk] = *(const half8*)((const char*)hbuf[PIN] + kk * 64 + lg * 16);    \
    float4v acc[7];                                                              \
    _Pragma("unroll") for (int tt = 0; tt < 7; ++tt) {                           \
      float xv = (float)CUR[tt];                                                 \
      acc[tt] = (float4v){xv, xv, xv, xv};                                       \
    }                                                                            \
    _Pragma("unroll") for (int kk = 0; kk < 4; ++kk)                             \
        _Pragma("unroll") for (int tt = 0; tt < 7; ++tt)                         \
            acc[tt] = __builtin_amdgcn_mfma_f32_16x16x32_f16(af[kk], wb[tt][kk], \
                                                             acc[tt], 0, 0, 0);  \
    float iv = sigmoidf_(acc[0][0]), fv = sigmoidf_(acc[1][0]);                  \
    float zv = tanhf_(acc[2][0]), ov = sigmoidf_(acc[3][0]);                     \
    float ibv = sigmoidf_(acc[4][0]), fbv = sigmoidf_(acc[5][0]);                \
    float dv = softplusf_(acc[6][0]);                                            \
    float cc = fv * c_s + iv * zv;                                               \
    cb_s = fbv * cb_s + ibv * zv;                                                \
    float cn = cb_s + (cc - cb_s) * __expf(-dv * dt);                            \
    float hn = ov * tanhf_(cn);                                                  \
    c_s = cn;                                                                    \
    hsave = hn;                                                                  \
    if (lg == 0) {                                                               \
      if ((T) == tend) {                                                         \
        out[b * HH + u] = hn;                                                    \
        out[BB * HH + b * HH + u] = cn;                                          \
      }                                                                          \
      hbuf[POUT][u] = (_Float16)hn;                                              \
    }                                                                            \
    __syncthreads();                                                             \
  } while (0)

  for (int tb = t0; tb <= tstop; tb += 2) {
    int tp2 = min(tb + 2, tstop) - t0, tp3 = min(tb + 3, tstop) - t0;
    nxt0 = *(const half8*)(xgp + (size_t)tp2 * stp);
    nxt1 = *(const half8*)(xgp + (size_t)tp3 * stp);
    STEP(tb, cur0, 0, 1);
    if (tb + 1 <= tstop) STEP(tb + 1, cur1, 1, 0);
    cur0 = nxt0;
    cur1 = nxt1;
  }
#undef STEP

  if (tstop < tend && lg == 0) {  // save state for next chunk
    st_h[b * HH + u] = (_Float16)hsave;
    st_c[b * HH + u] = c_s;
    st_cb[b * HH + u] = cb_s;
  }
}

extern "C" void kernel_launch(void* const* d_in, const int* in_sizes, int n_in,
                              void* d_out, int out_size, void* d_ws, size_t ws_size,
                              hipStream_t stream) {
  const float* x = (const float*)d_in[0];
  const float* dur = (const float*)d_in[1];
  const int* rep = (const int*)d_in[2];
  const float* Wx = (const float*)d_in[3];
  const float* Wh = (const float*)d_in[4];
  const float* bias = (const float*)d_in[5];
  float* out = (float*)d_out;
  char* ws = (char*)d_ws;

  size_t off = 0;
  _Float16* WxTp = (_Float16*)(ws + off); off += (size_t)NGP * DD * 2;
  _Float16* WhT = (_Float16*)(ws + off); off += (size_t)NG * DD * 2;
  float* bias_p = (float*)(ws + off); off += (size_t)NGP * 4;
  _Float16* st_h = (_Float16*)(ws + off); off += (size_t)BB * HH * 2;
  float* st_c = (float*)(ws + off); off += (size_t)BB * HH * 4;
  float* st_cb = (float*)(ws + off); off += (size_t)BB * HH * 4;
  _Float16* xgbuf = (_Float16*)(ws + off);

  size_t avail = ws_size > off ? ws_size - off : 0;
  size_t perT = (size_t)BB * NGP * 2;
  int Tc = (int)(avail / perT);
  if (Tc > TT) Tc = TT;
  if (Tc < 1) Tc = 1;

  int nprep = NGP * DD + NG * DD + NGP;
  hipLaunchKernelGGL(wtrans_k, dim3((nprep + 255) / 256), dim3(256), 0, stream,
                     Wx, Wh, bias, WxTp, WhT, bias_p);
  for (int t0 = 0; t0 < TT; t0 += Tc) {
    int t1 = t0 + Tc;
    if (t1 > TT) t1 = TT;
    int mtiles = (t1 - t0) * BB / 128;
    hipLaunchKernelGGL(xg_gemm_k, dim3(mtiles * 8), dim3(256), 0, stream,
                       x, WxTp, bias_p, xgbuf, t0);
    hipLaunchKernelGGL(rec_k, dim3(BB), dim3(512), 0, stream,
                       xgbuf, dur, rep, WhT, out, st_h, st_c, st_cb, t0, t1);
  }
}

// Round 6
// 202.509 us; speedup vs baseline: 1.7358x; 1.0522x over previous
//
#include <hip/hip_runtime.h>

#define TT 200
#define BB 256
#define DD 128
#define HH 128
#define NG 896    // 7*H semantic gate dim
#define NGP 1024  // padded: pcol = u*8 + gate, gate 7 = zero pad

typedef _Float16 half8 __attribute__((ext_vector_type(8)));
typedef _Float16 half4 __attribute__((ext_vector_type(4)));
typedef float float4v __attribute__((ext_vector_type(4)));

__device__ __forceinline__ float rcpf_(float x) { return __builtin_amdgcn_rcpf(x); }
__device__ __forceinline__ float sigmoidf_(float x) { return rcpf_(1.f + __expf(-x)); }
__device__ __forceinline__ float tanhf_(float x) { return 1.f - 2.f * rcpf_(__expf(2.f * x) + 1.f); }
// softplus(x) = max(x,0) + ln(1+exp(-|x|))
__device__ __forceinline__ float softplusf_(float x) {
  return fmaxf(x, 0.f) + 0.69314718056f * __log2f(1.f + __expf(-fabsf(x)));
}

// Weight prep: WxTp[pcol][k] (pcol=u*8+g, padded), WhT[col][k] (semantic), bias_p[pcol]
__global__ __launch_bounds__(256) void wtrans_k(const float* __restrict__ Wx,
    const float* __restrict__ Wh, const float* __restrict__ bias,
    _Float16* __restrict__ WxTp, _Float16* __restrict__ WhT, float* __restrict__ bias_p) {
  int idx = blockIdx.x * 256 + threadIdx.x;
  if (idx < NGP * DD) {  // WxTp
    int pcol = idx >> 7, k = idx & 127;
    int u = pcol >> 3, g = pcol & 7;
    WxTp[idx] = (g < 7) ? (_Float16)Wx[k * NG + g * HH + u] : (_Float16)0.f;
  } else if (idx < NGP * DD + NG * DD) {  // WhT
    int i2 = idx - NGP * DD;
    int col = i2 >> 7, k = i2 & 127;
    WhT[i2] = (_Float16)Wh[k * NG + col];
  } else if (idx < NGP * DD + NG * DD + NGP) {  // bias_p
    int pcol = idx - NGP * DD - NG * DD;
    int u = pcol >> 3, g = pcol & 7;
    bias_p[pcol] = (g < 7) ? bias[g * HH + u] : 0.f;
  }
}

// xg GEMM, A-tile staged once per block (coalesced), nt-loop inside.
// Block mt: chunk rows G in [mt*128,(mt+1)*128) -> fixed t, b in [b0,b0+128).
// xg[G][pcol] = x[b,t,:] @ WxTp[pcol,:] + bias_p[pcol]
__global__ __launch_bounds__(256, 2) void xg_gemm_k(const float* __restrict__ x,
    const _Float16* __restrict__ WxTp, const float* __restrict__ bias_p,
    _Float16* __restrict__ xg, int t0) {
  int mt = blockIdx.x;
  __shared__ _Float16 Ald[128][136];
  __shared__ _Float16 Bld[128][136];
  int tid = threadIdx.x;
  int G0 = mt * 128;
  int t = t0 + (G0 >> 8);
  int b0 = G0 & 255;
  {  // coalesced f32 load of x[b0..b0+128)[t][0..128) -> f16 in Ald
    int r = tid >> 5, kq = (tid & 31) << 2;
#pragma unroll
    for (int it = 0; it < 16; ++it) {
      int row = r + it * 8;
      float4v xv = *(const float4v*)(x + ((size_t)(b0 + row) * TT + t) * DD + kq);
      half4 h4 = {(_Float16)xv[0], (_Float16)xv[1], (_Float16)xv[2], (_Float16)xv[3]};
      *(half4*)&Ald[row][kq] = h4;
    }
  }
  __syncthreads();
  int wv = tid >> 6, l = tid & 63, lr = l & 15, lk8 = (l >> 4) << 3;
  // A-fragments in registers, reused across all 8 nt tiles
  half8 af[2][4];
#pragma unroll
  for (int mf = 0; mf < 2; ++mf)
#pragma unroll
    for (int kk = 0; kk < 4; ++kk)
      af[mf][kk] = *(const half8*)&Ald[wv * 32 + mf * 16 + lr][kk * 32 + lk8];

  for (int nt = 0; nt < 8; ++nt) {
    for (int i = tid; i < 128 * 16; i += 256) {
      int r = i >> 4, c8 = (i & 15) << 3;
      *(half8*)&Bld[r][c8] = *(const half8*)(WxTp + (size_t)(nt * 128 + r) * DD + c8);
    }
    __syncthreads();
    float4v acc[2][8];
#pragma unroll
    for (int a = 0; a < 2; ++a)
#pragma unroll
      for (int q = 0; q < 8; ++q) acc[a][q] = (float4v){0.f, 0.f, 0.f, 0.f};
#pragma unroll
    for (int kk = 0; kk < 4; ++kk) {
#pragma unroll
      for (int nf = 0; nf < 8; ++nf) {
        half8 bv = *(const half8*)&Bld[nf * 16 + lr][kk * 32 + lk8];
        acc[0][nf] = __builtin_amdgcn_mfma_f32_16x16x32_f16(af[0][kk], bv, acc[0][nf], 0, 0, 0);
        acc[1][nf] = __builtin_amdgcn_mfma_f32_16x16x32_f16(af[1][kk], bv, acc[1][nf], 0, 0, 0);
      }
    }
    int r4 = (l >> 4) << 2;
#pragma unroll
    for (int nf = 0; nf < 8; ++nf) {
      int col = nt * 128 + nf * 16 + lr;
      float bv = bias_p[col];
#pragma unroll
      for (int mf = 0; mf < 2; ++mf) {
        int row = G0 + wv * 32 + mf * 16 + r4;
#pragma unroll
        for (int rr = 0; rr < 4; ++rr) {
          xg[(size_t)(row + rr) * NGP + col] = (_Float16)(acc[mf][nf][rr] + bv);
        }
      }
    }
    __syncthreads();  // before next nt overwrites Bld
  }
}

// MFMA recurrence, one __syncthreads per step.
// 1 block/sample, 512 threads (8 waves). Wave w, lane l: lr=l&15, lg=l>>4.
// Unit u = w*16+lr. A = h broadcast to all 16 rows => component 0 of each
// partial C is the gate-tt partial preactivation for unit u. 4 INDEPENDENT
// partial MFMAs per gate (zero C) + scalar add tail: no 4-deep MFMA chain,
// no per-step acc-init movs. Each lane does the full state update for u
// (4x replicated over lg); lg==0 writes h / outputs.
__global__ __launch_bounds__(512, 2) void rec_k(const _Float16* __restrict__ xg,
    const float* __restrict__ dur, const int* __restrict__ rep,
    const _Float16* __restrict__ WhT, float* __restrict__ out,
    _Float16* __restrict__ st_h, float* __restrict__ st_c, float* __restrict__ st_cb,
    int t0, int t1) {
  int b = blockIdx.x, j = threadIdx.x;
  int tend = rep[b];
  if (t0 > tend) return;  // block-uniform
  int tstop = min(t1 - 1, tend);
  __shared__ __align__(16) _Float16 hbuf[2][HH];
  __shared__ float dlds[TT];
  int w = j >> 6, l = j & 63, lr = l & 15, lg = l >> 4;
  int u = w * 16 + lr;

  // B-fragments: wb[tt][kk] = WhT[col = tt*128+u][k = kk*32 + lg*8 .. +8]
  half8 wb[7][4];
#pragma unroll
  for (int tt = 0; tt < 7; ++tt) {
#pragma unroll
    for (int kk = 0; kk < 4; ++kk)
      wb[tt][kk] = *(const half8*)(WhT + (size_t)(tt * HH + u) * DD + kk * 32 + lg * 8);
  }
  for (int i = j; i < TT; i += 512) dlds[i] = dur[b * TT + i];
  float c_s = 0.f, cb_s = 0.f;
  if (lg == 0) {
    if (t0 == 0) {
      hbuf[0][u] = (_Float16)0.f;
    } else {
      hbuf[0][u] = st_h[b * HH + u];
    }
    hbuf[1][u] = (_Float16)0.f;
  }
  if (t0 != 0) {
    c_s = st_c[b * HH + u];
    cb_s = st_cb[b * HH + u];
  }
  __syncthreads();

  const float4v z4 = {0.f, 0.f, 0.f, 0.f};  // loop-invariant zero C
  const _Float16* xgp = xg + (size_t)b * NGP + u * 8;  // + step*stp, aligned 16B
  const size_t stp = (size_t)BB * NGP;
  half8 cur0, cur1, nxt0, nxt1;
  cur0 = *(const half8*)(xgp);
  cur1 = *(const half8*)(xgp + (size_t)(min(t0 + 1, tstop) - t0) * stp);
  float hsave = 0.f;

#define STEP(T, CUR, PIN, POUT)                                                  \
  do {                                                                           \
    float dt = dlds[T];                                                          \
    half8 af[4];                                                                 \
    _Pragma("unroll") for (int kk = 0; kk < 4; ++kk)                             \
        af[kk] = *(const half8*)((const char*)hbuf[PIN] + kk * 64 + lg * 16);    \
    float gv[7];                                                                 \
    _Pragma("unroll") for (int tt = 0; tt < 7; ++tt) {                           \
      float4v p0 = __builtin_amdgcn_mfma_f32_16x16x32_f16(af[0], wb[tt][0], z4, 0, 0, 0); \
      float4v p1 = __builtin_amdgcn_mfma_f32_16x16x32_f16(af[1], wb[tt][1], z4, 0, 0, 0); \
      float4v p2 = __builtin_amdgcn_mfma_f32_16x16x32_f16(af[2], wb[tt][2], z4, 0, 0, 0); \
      float4v p3 = __builtin_amdgcn_mfma_f32_16x16x32_f16(af[3], wb[tt][3], z4, 0, 0, 0); \
      gv[tt] = ((p0[0] + p1[0]) + (p2[0] + p3[0])) + (float)CUR[tt];             \
    }                                                                            \
    float iv = sigmoidf_(gv[0]), fv = sigmoidf_(gv[1]);                          \
    float zv = tanhf_(gv[2]), ov = sigmoidf_(gv[3]);                             \
    float ibv = sigmoidf_(gv[4]), fbv = sigmoidf_(gv[5]);                        \
    float dv = softplusf_(gv[6]);                                                \
    float cc = fv * c_s + iv * zv;                                               \
    cb_s = fbv * cb_s + ibv * zv;                                                \
    float cn = cb_s + (cc - cb_s) * __expf(-dv * dt);                            \
    float hn = ov * tanhf_(cn);                                                  \
    c_s = cn;                                                                    \
    hsave = hn;                                                                  \
    if (lg == 0) {                                                               \
      if ((T) == tend) {                                                         \
        out[b * HH + u] = hn;                                                    \
        out[BB * HH + b * HH + u] = cn;                                          \
      }                                                                          \
      hbuf[POUT][u] = (_Float16)hn;                                              \
    }                                                                            \
    __syncthreads();                                                             \
  } while (0)

  for (int tb = t0; tb <= tstop; tb += 2) {
    int tp2 = min(tb + 2, tstop) - t0, tp3 = min(tb + 3, tstop) - t0;
    nxt0 = *(const half8*)(xgp + (size_t)tp2 * stp);
    nxt1 = *(const half8*)(xgp + (size_t)tp3 * stp);
    STEP(tb, cur0, 0, 1);
    if (tb + 1 <= tstop) STEP(tb + 1, cur1, 1, 0);
    cur0 = nxt0;
    cur1 = nxt1;
  }
#undef STEP

  if (tstop < tend && lg == 0) {  // save state for next chunk
    st_h[b * HH + u] = (_Float16)hsave;
    st_c[b * HH + u] = c_s;
    st_cb[b * HH + u] = cb_s;
  }
}

extern "C" void kernel_launch(void* const* d_in, const int* in_sizes, int n_in,
                              void* d_out, int out_size, void* d_ws, size_t ws_size,
                              hipStream_t stream) {
  const float* x = (const float*)d_in[0];
  const float* dur = (const float*)d_in[1];
  const int* rep = (const int*)d_in[2];
  const float* Wx = (const float*)d_in[3];
  const float* Wh = (const float*)d_in[4];
  const float* bias = (const float*)d_in[5];
  float* out = (float*)d_out;
  char* ws = (char*)d_ws;

  size_t off = 0;
  _Float16* WxTp = (_Float16*)(ws + off); off += (size_t)NGP * DD * 2;
  _Float16* WhT = (_Float16*)(ws + off); off += (size_t)NG * DD * 2;
  float* bias_p = (float*)(ws + off); off += (size_t)NGP * 4;
  _Float16* st_h = (_Float16*)(ws + off); off += (size_t)BB * HH * 2;
  float* st_c = (float*)(ws + off); off += (size_t)BB * HH * 4;
  float* st_cb = (float*)(ws + off); off += (size_t)BB * HH * 4;
  _Float16* xgbuf = (_Float16*)(ws + off);

  size_t avail = ws_size > off ? ws_size - off : 0;
  size_t perT = (size_t)BB * NGP * 2;
  int Tc = (int)(avail / perT);
  if (Tc > TT) Tc = TT;
  if (Tc < 1) Tc = 1;

  int nprep = NGP * DD + NG * DD + NGP;
  hipLaunchKernelGGL(wtrans_k, dim3((nprep + 255) / 256), dim3(256), 0, stream,
                     Wx, Wh, bias, WxTp, WhT, bias_p);
  for (int t0 = 0; t0 < TT; t0 += Tc) {
    int t1 = t0 + Tc;
    if (t1 > TT) t1 = TT;
    int mtiles = (t1 - t0) * BB / 128;
    hipLaunchKernelGGL(xg_gemm_k, dim3(mtiles), dim3(256), 0, stream,
                       x, WxTp, bias_p, xgbuf, t0);
    hipLaunchKernelGGL(rec_k, dim3(BB), dim3(512), 0, stream,
                       xgbuf, dur, rep, WhT, out, st_h, st_c, st_cb, t0, t1);
  }
}